// Round 19
// baseline (147.025 us; speedup 1.0000x reference)
//
#include <hip/hip_runtime.h>
#include <math.h>

#define EPS 1e-4f

// dims: B=2, T=2048, D=1024, HEADS=16, DH=64, E=4096, TOK=4096, BH=32

typedef __attribute__((ext_vector_type(8))) short bf16x8;
typedef __attribute__((ext_vector_type(8))) unsigned short u16x8;
typedef __attribute__((ext_vector_type(4))) float f32x4;

#define MFMA(a, b, c) __builtin_amdgcn_mfma_f32_16x16x32_bf16(a, b, c, 0, 0, 0)

__device__ __forceinline__ unsigned short f2b(float f) {
    unsigned int u = __float_as_uint(f);
    u += 0x7fffu + ((u >> 16) & 1u);   // RNE
    return (unsigned short)(u >> 16);
}
__device__ __forceinline__ float b2f(unsigned short u) {
    return __uint_as_float(((unsigned int)u) << 16);
}
__device__ __forceinline__ unsigned int cvtpk(float a, float b) {
    unsigned int r;
    asm("v_cvt_pk_bf16_f32 %0, %1, %2" : "=v"(r) : "v"(a), "v"(b));
    return r;   // lo16 = bf16(a), hi16 = bf16(b)
}

typedef __attribute__((address_space(1))) const unsigned int as1_u32;
typedef __attribute__((address_space(3))) unsigned int as3_u32;
__device__ __forceinline__ void gl_lds16(const unsigned short* g, unsigned short* l) {
    __builtin_amdgcn_global_load_lds((as1_u32*)g, (as3_u32*)l, 16, 0, 0);
}

// ---------------------------------------------------------------------------
// fp32 -> bf16 convert for X, Win, Wout in ONE launch. 4608 blocks x 256.
// ---------------------------------------------------------------------------
__global__ __launch_bounds__(256)
void sga_f2b_all(const float* __restrict__ X, const float* __restrict__ Win,
                 const float* __restrict__ Wout,
                 unsigned short* __restrict__ Xb, unsigned short* __restrict__ Winb,
                 unsigned short* __restrict__ Woutb) {
    const int i = blockIdx.x * 256 + threadIdx.x;   // 0..1179647
    const float* src; unsigned short* dst; int off;
    if (i < 524288)        { src = X;    dst = Xb;    off = i; }
    else if (i < 1048576)  { src = Win;  dst = Winb;  off = i - 524288; }
    else                   { src = Wout; dst = Woutb; off = i - 1048576; }
    const float4* s = (const float4*)src + off * 2;
    float4 a = s[0], b = s[1];
    uint4 o;
    o.x = (unsigned)f2b(a.x) | ((unsigned)f2b(a.y) << 16);
    o.y = (unsigned)f2b(a.z) | ((unsigned)f2b(a.w) << 16);
    o.z = (unsigned)f2b(b.x) | ((unsigned)f2b(b.y) << 16);
    o.w = (unsigned)f2b(b.z) | ((unsigned)f2b(b.w) << 16);
    *((uint4*)dst + off) = o;
}

// ---------------------------------------------------------------------------
// GEMM1, m97 main loop; C^T fragment layout (lane col=lr=token, regs=n):
// Q/K/G written as ushort4, fused q2/k2 norms with 2 shfl_xor per m-tile.
// ---------------------------------------------------------------------------
__global__ __launch_bounds__(256)
void sga_gemm1(const unsigned short* __restrict__ Xb, const unsigned short* __restrict__ Wb,
               const float* __restrict__ bin,
               unsigned short* __restrict__ Qb, unsigned short* __restrict__ Kb,
               unsigned short* __restrict__ Vt, unsigned short* __restrict__ Gb,
               float* __restrict__ q2s, float* __restrict__ k2s)
{
    __shared__ unsigned short As[128 * 64];
    __shared__ unsigned short Bs[128 * 64];
    const int tid = threadIdx.x;
    const int lane = tid & 63, w = tid >> 6;
    const int lr = lane & 15, lg = lane >> 4;
    const int wm = w & 1, wn = w >> 1;
    const int m0 = blockIdx.y * 128, n0 = blockIdx.x * 128;

    const int sr = tid >> 3, sc8 = tid & 7;
    const int gch = sc8 ^ (sr & 7);
    const unsigned short* aBase = Xb + (m0 + sr) * 1024 + gch * 8;
    const unsigned short* bBase = Wb + (n0 + sr) * 1024 + gch * 8;
    unsigned short* aDst = &As[w * 512];
    unsigned short* bDst = &Bs[w * 512];

    f32x4 acc[4][4] = {};

    for (int kt = 0; kt < 16; ++kt) {
        __syncthreads();
        #pragma unroll
        for (int c = 0; c < 4; ++c)
            gl_lds16(aBase + c * 32768 + kt * 64, aDst + c * 2048);
        #pragma unroll
        for (int c = 0; c < 4; ++c)
            gl_lds16(bBase + c * 32768 + kt * 64, bDst + c * 2048);
        __syncthreads();

        #pragma unroll
        for (int ks = 0; ks < 2; ++ks) {
            bf16x8 af[4], bfr[4];
            #pragma unroll
            for (int i = 0; i < 4; ++i) {
                const int row = wm * 64 + i * 16 + lr;
                af[i] = *(const bf16x8*)&As[row * 64 + (((ks * 4 + lg) ^ (row & 7)) * 8)];
            }
            #pragma unroll
            for (int i = 0; i < 4; ++i) {
                const int row = wn * 64 + i * 16 + lr;
                bfr[i] = *(const bf16x8*)&Bs[row * 64 + (((ks * 4 + lg) ^ (row & 7)) * 8)];
            }
            #pragma unroll
            for (int mi = 0; mi < 4; ++mi)
                #pragma unroll
                for (int ni = 0; ni < 4; ++ni)
                    acc[mi][ni] = MFMA(bfr[ni], af[mi], acc[mi][ni]);   // C^T layout
        }
    }

    // epilogue scatter + fused norms (C^T fragments: token = lr, n = lg*4+r)
    const int bb = m0 >> 11;
    const bool qkBlock = ((n0 & 128) == 0);
    #pragma unroll
    for (int mi = 0; mi < 4; ++mi) {
        const int tok = m0 + wm * 64 + mi * 16 + lr;
        const int tloc = tok & 2047;
        float s2 = 0.f;
        #pragma unroll
        for (int ni = 0; ni < 4; ++ni) {
            const int n = n0 + wn * 64 + ni * 16 + lg * 4;
            const int h = n >> 8, cc = n & 255;
            const int part = cc >> 6, j0 = cc & 63;
            const int bh = bb * 16 + h;
            f32x4 bz = *(const f32x4*)&bin[n];
            f32x4 v = acc[mi][ni];
            unsigned short e0 = f2b(v[0] + bz[0]), e1 = f2b(v[1] + bz[1]),
                           e2 = f2b(v[2] + bz[2]), e3 = f2b(v[3] + bz[3]);
            if (qkBlock) {
                float f0 = b2f(e0), f1 = b2f(e1), f2v = b2f(e2), f3 = b2f(e3);
                s2 += f0 * f0 + f1 * f1 + f2v * f2v + f3 * f3;
            }
            if (part == 2) {
                Vt[(bh * 64 + j0 + 0) * 2048 + tloc] = e0;
                Vt[(bh * 64 + j0 + 1) * 2048 + tloc] = e1;
                Vt[(bh * 64 + j0 + 2) * 2048 + tloc] = e2;
                Vt[(bh * 64 + j0 + 3) * 2048 + tloc] = e3;
            } else {
                unsigned short* dst = (part == 0) ? Qb : ((part == 1) ? Kb : Gb);
                *(ushort4*)&dst[(bh * 2048 + tloc) * 64 + j0] =
                    make_ushort4(e0, e1, e2, e3);
            }
        }
        if (qkBlock) {
            s2 += __shfl_xor(s2, 16, 64);
            s2 += __shfl_xor(s2, 32, 64);
            if (lg == 0) {
                const int bh = bb * 16 + (n0 >> 8);
                float* __restrict__ dstn = wn ? k2s : q2s;
                dstn[bh * 2048 + tloc] = s2;
            }
        }
    }
}

// ---------------------------------------------------------------------------
// Attention — R12-proven structure (reg-staged K/V dbuf, Wlds slab, KSPLIT=3,
// XCD-cluster decode) with PV MFMA operands SWAPPED (O^T layout: lane holds
// 4 consecutive dh per q) -> epilogue 32 scalar stores become 8 uint2 stores,
// and partials are PRE-GATED by G (exact: g constant across partials).
// ---------------------------------------------------------------------------
__global__ __launch_bounds__(256, 3)
void sga_attn(const unsigned short* __restrict__ Qb, const unsigned short* __restrict__ Kb,
              const unsigned short* __restrict__ Vt, const unsigned short* __restrict__ Gb,
              const float* __restrict__ q2s, const float* __restrict__ k2s,
              unsigned short* __restrict__ Op0, unsigned short* __restrict__ Op1,
              unsigned short* __restrict__ Op2,
              float* __restrict__ Sw0, float* __restrict__ Sw1, float* __restrict__ Sw2)
{
    __shared__ unsigned short Klds[2 * 4096];   // [buf][row 64][64] swizzled
    __shared__ unsigned short Vlds[2 * 4096];
    __shared__ unsigned short Wlds[4 * 2048];   // per-wave [row 32][64] swizzled

    const int tid = threadIdx.x;
    const int lane = tid & 63, w = tid >> 6;
    const int lr = lane & 15, lg = lane >> 4;

    // XCD-cluster decode: 1536 blocks = 8 xcd x 12 groups x 16 qt (bijective)
    const int lin = blockIdx.x;
    const int xcd = lin & 7, rem = lin >> 3;        // rem 0..191
    const int gid = xcd * 12 + (rem >> 4);          // 0..95
    const int qt = rem & 15;
    const int half = gid >> 5, bh = gid & 31;       // half 0..2, bh 0..31
    const int q0 = qt * 128 + w * 32;
    const int kbeg = half * 11;
    const int kend = (half == 2) ? 32 : (kbeg + 11);

    unsigned short* wl = &Wlds[w * 2048];
    unsigned short* __restrict__ Op = (half == 0) ? Op0 : ((half == 1) ? Op1 : Op2);
    float* __restrict__ Sw = (half == 0) ? Sw0 : ((half == 1) ? Sw1 : Sw2);

    // ---- staging addressing (each wave stages 16 rows of each 64x64 tile)
    const int srow = w * 16 + (lane >> 2);     // tile row 0..63
    const int sc = (lane & 3) * 2;             // 16B-chunk pair {sc, sc+1} of 8
    const unsigned short* Kg = Kb + (bh * 2048 + srow) * 64 + sc * 8;  // + kt*4096
    const unsigned short* Vg = Vt + (bh * 64 + srow) * 2048 + sc * 8;  // + kt*64
    const int swz0 = srow * 64 + ((sc ^ (srow & 7)) * 8);
    const int swz1 = srow * 64 + (((sc + 1) ^ (srow & 7)) * 8);

    // ---- Q fragments (B-operand): Q[q0+g*16+lr][lg*8+e (+32)]
    bf16x8 qf[2][2];
    #pragma unroll
    for (int g = 0; g < 2; ++g) {
        const unsigned short* qp = Qb + (bh * 2048 + q0 + g * 16 + lr) * 64 + lg * 8;
        qf[g][0] = *(const bf16x8*)qp;
        qf[g][1] = *(const bf16x8*)(qp + 32);
    }
    float q2v[2];
    q2v[0] = q2s[bh * 2048 + q0 + lr];
    q2v[1] = q2s[bh * 2048 + q0 + 16 + lr];

    f32x4 oacc[2][4] = {};
    float sumw[2] = {0.f, 0.f};

    // ---- prologue: stage kbeg into buf 0
    uint4 ks0, ks1, vs0, vs1;
    {
        const unsigned short* kp = Kg + kbeg * 4096;
        ks0 = *(const uint4*)kp; ks1 = *(const uint4*)(kp + 8);
        const unsigned short* vp = Vg + kbeg * 64;
        vs0 = *(const uint4*)vp; vs1 = *(const uint4*)(vp + 8);
    }
    *(uint4*)&Klds[swz0] = ks0; *(uint4*)&Klds[swz1] = ks1;
    *(uint4*)&Vlds[swz0] = vs0; *(uint4*)&Vlds[swz1] = vs1;
    __syncthreads();

    int buf = 0;
    for (int kt = kbeg; kt < kend; ++kt) {
        const int k0 = kt * 64;
        const bool more = (kt + 1 < kend);

        // issue next-tile stage loads early (hide HBM/L2 latency under compute)
        if (more) {
            const unsigned short* kp = Kg + (kt + 1) * 4096;
            ks0 = *(const uint4*)kp; ks1 = *(const uint4*)(kp + 8);
            const unsigned short* vp = Vg + (kt + 1) * 64;
            vs0 = *(const uint4*)vp; vs1 = *(const uint4*)(vp + 8);
        }

        f32x4 k2v[4];
        #pragma unroll
        for (int nf = 0; nf < 4; ++nf)
            k2v[nf] = *(const f32x4*)&k2s[bh * 2048 + k0 + nf * 16 + lg * 4];

        // ---- QK^T swapped, K frags from swizzled LDS
        f32x4 sa[2][4] = {};
        const unsigned short* kb = &Klds[buf * 4096];
        __builtin_amdgcn_s_setprio(1);
        #pragma unroll
        for (int nf = 0; nf < 4; ++nf) {
            const int row = nf * 16 + lr;
            bf16x8 kf0 = *(const bf16x8*)&kb[row * 64 + ((lg ^ (row & 7)) * 8)];
            bf16x8 kf1 = *(const bf16x8*)&kb[row * 64 + (((4 + lg) ^ (row & 7)) * 8)];
            #pragma unroll
            for (int g = 0; g < 2; ++g) {
                sa[g][nf] = MFMA(kf0, qf[g][0], sa[g][nf]);
                sa[g][nf] = MFMA(kf1, qf[g][1], sa[g][nf]);
            }
        }
        __builtin_amdgcn_s_setprio(0);

        // ---- Shepard weights (sqrt-free), pack bf16, stash W[q][k] in slab
        #pragma unroll
        for (int g = 0; g < 2; ++g) {
            const int row = g * 16 + lr;
            #pragma unroll
            for (int nf = 0; nf < 4; ++nf) {
                float wv[4];
                #pragma unroll
                for (int r = 0; r < 4; ++r) {
                    float d2 = fmaf(-2.0f, sa[g][nf][r], q2v[g] + k2v[nf][r]);
                    d2 = fmaxf(d2, 1e-8f);
                    wv[r] = __builtin_amdgcn_rcpf(d2);
                    sumw[g] += wv[r];
                }
                uint2 pk;
                pk.x = cvtpk(wv[0], wv[1]);
                pk.y = cvtpk(wv[2], wv[3]);
                const int c = 2 * nf + (lg >> 1);
                *(uint2*)&wl[row * 64 + ((c ^ (row & 7)) * 8) + (lg & 1) * 4] = pk;
            }
        }

        // ---- PV (operands SWAPPED -> O^T): A = V frags, B = W frags
        bf16x8 pa[2][2];
        #pragma unroll
        for (int g = 0; g < 2; ++g) {
            const int row = g * 16 + lr;
            pa[g][0] = *(const bf16x8*)&wl[row * 64 + ((lg ^ (row & 7)) * 8)];
            pa[g][1] = *(const bf16x8*)&wl[row * 64 + (((4 + lg) ^ (row & 7)) * 8)];
        }
        const unsigned short* vb = &Vlds[buf * 4096];
        __builtin_amdgcn_s_setprio(1);
        #pragma unroll
        for (int vf = 0; vf < 4; ++vf) {
            const int row = vf * 16 + lr;
            bf16x8 v0 = *(const bf16x8*)&vb[row * 64 + ((lg ^ (row & 7)) * 8)];
            bf16x8 v1 = *(const bf16x8*)&vb[row * 64 + (((4 + lg) ^ (row & 7)) * 8)];
            #pragma unroll
            for (int g = 0; g < 2; ++g) {
                oacc[g][vf] = MFMA(v0, pa[g][0], oacc[g][vf]);
                oacc[g][vf] = MFMA(v1, pa[g][1], oacc[g][vf]);
            }
        }
        __builtin_amdgcn_s_setprio(0);

        // ---- write staged regs into the other buffer, sync, swap
        if (more) {
            const int bo = (buf ^ 1) * 4096;
            *(uint4*)&Klds[bo + swz0] = ks0; *(uint4*)&Klds[bo + swz1] = ks1;
            *(uint4*)&Vlds[bo + swz0] = vs0; *(uint4*)&Vlds[bo + swz1] = vs1;
            __syncthreads();
            buf ^= 1;
        }
    }

    // wave-reduce sum-of-weights (lanes with same lr cover disjoint k)
    #pragma unroll
    for (int g = 0; g < 2; ++g) {
        sumw[g] += __shfl_xor(sumw[g], 16, 64);
        sumw[g] += __shfl_xor(sumw[g], 32, 64);
    }

    // epilogue: pre-gated unnormalized partial O (bf16, O^T frag layout:
    // lane holds q = q0+g*16+lr, dh = vf*16+lg*4+r) + partial sums
    #pragma unroll
    for (int g = 0; g < 2; ++g) {
        const int t = q0 + g * 16 + lr;
        #pragma unroll
        for (int vf = 0; vf < 4; ++vf) {
            const int dh0 = vf * 16 + lg * 4;
            ushort4 g4 = *(const ushort4*)&Gb[(bh * 2048 + t) * 64 + dh0];
            f32x4 v = oacc[g][vf];
            uint2 pk;
            pk.x = cvtpk(v[0] * b2f(g4.x), v[1] * b2f(g4.y));
            pk.y = cvtpk(v[2] * b2f(g4.z), v[3] * b2f(g4.w));
            *(uint2*)&Op[(bh * 2048 + t) * 64 + dh0] = pk;
        }
    }
    if (lg == 0) {
        Sw[bh * 2048 + q0 + lr]      = sumw[0];
        Sw[bh * 2048 + q0 + 16 + lr] = sumw[1];
    }
}

// ---------------------------------------------------------------------------
// Combine: H[tok][h*64+dh] = (o0+o1+o2)/(EPS+s0+s1+s2), bf16 (pre-gated).
// ---------------------------------------------------------------------------
__global__ __launch_bounds__(256)
void sga_combine(const unsigned short* __restrict__ Op0, const unsigned short* __restrict__ Op1,
                 const unsigned short* __restrict__ Op2,
                 const float* __restrict__ Sw0, const float* __restrict__ Sw1,
                 const float* __restrict__ Sw2,
                 unsigned short* __restrict__ Hb)
{
    const int idx = blockIdx.x * 256 + threadIdx.x;   // one per 8 dh
    const int t16 = idx >> 3;                          // bh*2048 + t
    const int dq = (idx & 7) << 3;
    u16x8 a = *(const u16x8*)&Op0[t16 * 64 + dq];
    u16x8 b = *(const u16x8*)&Op1[t16 * 64 + dq];
    u16x8 c = *(const u16x8*)&Op2[t16 * 64 + dq];
    const float s = Sw0[t16] + Sw1[t16] + Sw2[t16];
    const float inv = __builtin_amdgcn_rcpf(EPS + s);
    const int bh = t16 >> 11, tloc = t16 & 2047;
    const int bb = bh >> 4, h = bh & 15;
    u16x8 o;
    #pragma unroll
    for (int j = 0; j < 8; ++j)
        o[j] = f2b((b2f(a[j]) + b2f(b[j]) + b2f(c[j])) * inv);
    *(u16x8*)&Hb[(bb * 2048 + tloc) * 1024 + h * 64 + dq] = o;
}

// ---------------------------------------------------------------------------
// GEMM2, m97 structure, BM=64 x BN=128 (512 blocks -> 2 blocks/CU):
// Y = Hb*Woutb^T + bout
// ---------------------------------------------------------------------------
__global__ __launch_bounds__(256)
void sga_gemm2(const unsigned short* __restrict__ Hb, const unsigned short* __restrict__ Wb,
               const float* __restrict__ bout, float* __restrict__ Y)
{
    __shared__ unsigned short As[64 * 64];
    __shared__ unsigned short Bs[128 * 64];
    const int tid = threadIdx.x;
    const int lane = tid & 63, w = tid >> 6;
    const int lr = lane & 15, lg = lane >> 4;
    const int wm = w & 1, wn = w >> 1;
    const int m0 = blockIdx.y * 64, n0 = blockIdx.x * 128;

    const int sr = tid >> 3, sc8 = tid & 7;
    const int gch = sc8 ^ (sr & 7);
    const unsigned short* aBase = Hb + (m0 + sr) * 1024 + gch * 8;
    const unsigned short* bBase = Wb + (n0 + sr) * 1024 + gch * 8;
    unsigned short* aDst = &As[w * 512];
    unsigned short* bDst = &Bs[w * 512];

    f32x4 acc[2][4] = {};

    for (int kt = 0; kt < 16; ++kt) {
        __syncthreads();
        #pragma unroll
        for (int c = 0; c < 2; ++c)
            gl_lds16(aBase + c * 32768 + kt * 64, aDst + c * 2048);
        #pragma unroll
        for (int c = 0; c < 4; ++c)
            gl_lds16(bBase + c * 32768 + kt * 64, bDst + c * 2048);
        __syncthreads();

        #pragma unroll
        for (int ks = 0; ks < 2; ++ks) {
            bf16x8 af[2], bfr[4];
            #pragma unroll
            for (int i = 0; i < 2; ++i) {
                const int row = wm * 32 + i * 16 + lr;
                af[i] = *(const bf16x8*)&As[row * 64 + (((ks * 4 + lg) ^ (row & 7)) * 8)];
            }
            #pragma unroll
            for (int i = 0; i < 4; ++i) {
                const int row = wn * 64 + i * 16 + lr;
                bfr[i] = *(const bf16x8*)&Bs[row * 64 + (((ks * 4 + lg) ^ (row & 7)) * 8)];
            }
            #pragma unroll
            for (int mi = 0; mi < 2; ++mi)
                #pragma unroll
                for (int ni = 0; ni < 4; ++ni)
                    acc[mi][ni] = MFMA(af[mi], bfr[ni], acc[mi][ni]);
        }
    }

    #pragma unroll
    for (int mf = 0; mf < 2; ++mf) {
        const int m = m0 + wm * 32 + mf * 16 + lg * 4;
        #pragma unroll
        for (int nf = 0; nf < 4; ++nf) {
            const int n = n0 + wn * 64 + nf * 16 + lr;
            const float bz = bout[n];
            f32x4 v = acc[mf][nf];
            #pragma unroll
            for (int r = 0; r < 4; ++r)
                Y[(m + r) * 1024 + n] = v[r] + bz;
        }
    }
}

extern "C" void kernel_launch(void* const* d_in, const int* in_sizes, int n_in,
                              void* d_out, int out_size, void* d_ws, size_t ws_size,
                              hipStream_t stream) {
    const float* X    = (const float*)d_in[0];
    const float* Win  = (const float*)d_in[1];
    const float* bin  = (const float*)d_in[2];
    const float* Wout = (const float*)d_in[3];
    const float* bout = (const float*)d_in[4];
    float* Y = (float*)d_out;

    const int PER = 32 * 2048 * 64;        // 4,194,304 elems per Q/K/V/G tensor
    unsigned short* Qb   = (unsigned short*)d_ws;
    unsigned short* Kb   = Qb + PER;
    unsigned short* Vt   = Kb + PER;
    unsigned short* Gb   = Vt + PER;
    unsigned short* Hb   = Gb + PER;       // 4096*1024
    unsigned short* Xb   = Hb + PER;
    unsigned short* Winb = Xb + PER;
    unsigned short* Woutb= Winb + PER;
    float* q2s = (float*)(Woutb + 1024 * 1024);
    float* k2s = q2s + 32 * 2048;
    float* Sw0 = k2s + 32 * 2048;
    float* Sw1 = Sw0 + 32 * 2048;
    float* Sw2 = Sw1 + 32 * 2048;
    unsigned short* Op2 = (unsigned short*)(Sw2 + 32 * 2048);
    // partial-O buffers 0/1 alias Xb/Winb (dead after gemm1; stream is serial)
    unsigned short* Op0 = Xb;
    unsigned short* Op1 = Winb;

    sga_f2b_all<<<4608, 256, 0, stream>>>(X, Win, Wout, Xb, Winb, Woutb);
    sga_gemm1<<<dim3(32, 32), 256, 0, stream>>>(Xb, Winb, bin, Qb, Kb, Vt, Gb, q2s, k2s);
    sga_attn <<<1536, 256, 0, stream>>>(Qb, Kb, Vt, Gb, q2s, k2s, Op0, Op1, Op2, Sw0, Sw1, Sw2);
    sga_combine<<<2048, 256, 0, stream>>>(Op0, Op1, Op2, Sw0, Sw1, Sw2, Hb);
    sga_gemm2<<<dim3(8, 64), 256, 0, stream>>>(Hb, Woutb, bout, Y);
}

// Round 20
// 142.028 us; speedup vs baseline: 1.0352x; 1.0352x over previous
//
#include <hip/hip_runtime.h>
#include <math.h>

#define EPS 1e-4f

// dims: B=2, T=2048, D=1024, HEADS=16, DH=64, E=4096, TOK=4096, BH=32

typedef __attribute__((ext_vector_type(8))) short bf16x8;
typedef __attribute__((ext_vector_type(8))) unsigned short u16x8;
typedef __attribute__((ext_vector_type(4))) float f32x4;

#define MFMA(a, b, c) __builtin_amdgcn_mfma_f32_16x16x32_bf16(a, b, c, 0, 0, 0)

__device__ __forceinline__ unsigned short f2b(float f) {
    unsigned int u = __float_as_uint(f);
    u += 0x7fffu + ((u >> 16) & 1u);   // RNE
    return (unsigned short)(u >> 16);
}
__device__ __forceinline__ float b2f(unsigned short u) {
    return __uint_as_float(((unsigned int)u) << 16);
}
__device__ __forceinline__ unsigned int cvtpk(float a, float b) {
    unsigned int r;
    asm("v_cvt_pk_bf16_f32 %0, %1, %2" : "=v"(r) : "v"(a), "v"(b));
    return r;   // lo16 = bf16(a), hi16 = bf16(b)
}

typedef __attribute__((address_space(1))) const unsigned int as1_u32;
typedef __attribute__((address_space(3))) unsigned int as3_u32;
__device__ __forceinline__ void gl_lds16(const unsigned short* g, unsigned short* l) {
    __builtin_amdgcn_global_load_lds((as1_u32*)g, (as3_u32*)l, 16, 0, 0);
}

// ---------------------------------------------------------------------------
// fp32 -> bf16 convert for X, Win, Wout in ONE launch. 4608 blocks x 256.
// ---------------------------------------------------------------------------
__global__ __launch_bounds__(256)
void sga_f2b_all(const float* __restrict__ X, const float* __restrict__ Win,
                 const float* __restrict__ Wout,
                 unsigned short* __restrict__ Xb, unsigned short* __restrict__ Winb,
                 unsigned short* __restrict__ Woutb) {
    const int i = blockIdx.x * 256 + threadIdx.x;   // 0..1179647
    const float* src; unsigned short* dst; int off;
    if (i < 524288)        { src = X;    dst = Xb;    off = i; }
    else if (i < 1048576)  { src = Win;  dst = Winb;  off = i - 524288; }
    else                   { src = Wout; dst = Woutb; off = i - 1048576; }
    const float4* s = (const float4*)src + off * 2;
    float4 a = s[0], b = s[1];
    uint4 o;
    o.x = (unsigned)f2b(a.x) | ((unsigned)f2b(a.y) << 16);
    o.y = (unsigned)f2b(a.z) | ((unsigned)f2b(a.w) << 16);
    o.z = (unsigned)f2b(b.x) | ((unsigned)f2b(b.y) << 16);
    o.w = (unsigned)f2b(b.z) | ((unsigned)f2b(b.w) << 16);
    *((uint4*)dst + off) = o;
}

// ---------------------------------------------------------------------------
// GEMM1, m97 main loop; C^T fragment layout (lane col=lr=token, regs=n):
// Q/K/G written as ushort4, fused q2/k2 norms with 2 shfl_xor per m-tile.
// ---------------------------------------------------------------------------
__global__ __launch_bounds__(256)
void sga_gemm1(const unsigned short* __restrict__ Xb, const unsigned short* __restrict__ Wb,
               const float* __restrict__ bin,
               unsigned short* __restrict__ Qb, unsigned short* __restrict__ Kb,
               unsigned short* __restrict__ Vt, unsigned short* __restrict__ Gb,
               float* __restrict__ q2s, float* __restrict__ k2s)
{
    __shared__ unsigned short As[128 * 64];
    __shared__ unsigned short Bs[128 * 64];
    const int tid = threadIdx.x;
    const int lane = tid & 63, w = tid >> 6;
    const int lr = lane & 15, lg = lane >> 4;
    const int wm = w & 1, wn = w >> 1;
    const int m0 = blockIdx.y * 128, n0 = blockIdx.x * 128;

    const int sr = tid >> 3, sc8 = tid & 7;
    const int gch = sc8 ^ (sr & 7);
    const unsigned short* aBase = Xb + (m0 + sr) * 1024 + gch * 8;
    const unsigned short* bBase = Wb + (n0 + sr) * 1024 + gch * 8;
    unsigned short* aDst = &As[w * 512];
    unsigned short* bDst = &Bs[w * 512];

    f32x4 acc[4][4] = {};

    for (int kt = 0; kt < 16; ++kt) {
        __syncthreads();
        #pragma unroll
        for (int c = 0; c < 4; ++c)
            gl_lds16(aBase + c * 32768 + kt * 64, aDst + c * 2048);
        #pragma unroll
        for (int c = 0; c < 4; ++c)
            gl_lds16(bBase + c * 32768 + kt * 64, bDst + c * 2048);
        __syncthreads();

        #pragma unroll
        for (int ks = 0; ks < 2; ++ks) {
            bf16x8 af[4], bfr[4];
            #pragma unroll
            for (int i = 0; i < 4; ++i) {
                const int row = wm * 64 + i * 16 + lr;
                af[i] = *(const bf16x8*)&As[row * 64 + (((ks * 4 + lg) ^ (row & 7)) * 8)];
            }
            #pragma unroll
            for (int i = 0; i < 4; ++i) {
                const int row = wn * 64 + i * 16 + lr;
                bfr[i] = *(const bf16x8*)&Bs[row * 64 + (((ks * 4 + lg) ^ (row & 7)) * 8)];
            }
            #pragma unroll
            for (int mi = 0; mi < 4; ++mi)
                #pragma unroll
                for (int ni = 0; ni < 4; ++ni)
                    acc[mi][ni] = MFMA(bfr[ni], af[mi], acc[mi][ni]);   // C^T layout
        }
    }

    // epilogue scatter + fused norms (C^T fragments: token = lr, n = lg*4+r)
    const int bb = m0 >> 11;
    const bool qkBlock = ((n0 & 128) == 0);
    #pragma unroll
    for (int mi = 0; mi < 4; ++mi) {
        const int tok = m0 + wm * 64 + mi * 16 + lr;
        const int tloc = tok & 2047;
        float s2 = 0.f;
        #pragma unroll
        for (int ni = 0; ni < 4; ++ni) {
            const int n = n0 + wn * 64 + ni * 16 + lg * 4;
            const int h = n >> 8, cc = n & 255;
            const int part = cc >> 6, j0 = cc & 63;
            const int bh = bb * 16 + h;
            f32x4 bz = *(const f32x4*)&bin[n];
            f32x4 v = acc[mi][ni];
            unsigned short e0 = f2b(v[0] + bz[0]), e1 = f2b(v[1] + bz[1]),
                           e2 = f2b(v[2] + bz[2]), e3 = f2b(v[3] + bz[3]);
            if (qkBlock) {
                float f0 = b2f(e0), f1 = b2f(e1), f2v = b2f(e2), f3 = b2f(e3);
                s2 += f0 * f0 + f1 * f1 + f2v * f2v + f3 * f3;
            }
            if (part == 2) {
                Vt[(bh * 64 + j0 + 0) * 2048 + tloc] = e0;
                Vt[(bh * 64 + j0 + 1) * 2048 + tloc] = e1;
                Vt[(bh * 64 + j0 + 2) * 2048 + tloc] = e2;
                Vt[(bh * 64 + j0 + 3) * 2048 + tloc] = e3;
            } else {
                unsigned short* dst = (part == 0) ? Qb : ((part == 1) ? Kb : Gb);
                *(ushort4*)&dst[(bh * 2048 + tloc) * 64 + j0] =
                    make_ushort4(e0, e1, e2, e3);
            }
        }
        if (qkBlock) {
            s2 += __shfl_xor(s2, 16, 64);
            s2 += __shfl_xor(s2, 32, 64);
            if (lg == 0) {
                const int bh = bb * 16 + (n0 >> 8);
                float* __restrict__ dstn = wn ? k2s : q2s;
                dstn[bh * 2048 + tloc] = s2;
            }
        }
    }
}

// ---------------------------------------------------------------------------
// Attention — R12-proven kernel (reg-staged K/V dbuf, Wlds slab, KSPLIT=3,
// XCD-cluster decode). 59.4us, VGPR 80, zero spill.
// ---------------------------------------------------------------------------
__global__ __launch_bounds__(256, 3)
void sga_attn(const unsigned short* __restrict__ Qb, const unsigned short* __restrict__ Kb,
              const unsigned short* __restrict__ Vt,
              const float* __restrict__ q2s, const float* __restrict__ k2s,
              unsigned short* __restrict__ Op0, unsigned short* __restrict__ Op1,
              unsigned short* __restrict__ Op2,
              float* __restrict__ Sw0, float* __restrict__ Sw1, float* __restrict__ Sw2)
{
    __shared__ unsigned short Klds[2 * 4096];   // [buf][row 64][64] swizzled
    __shared__ unsigned short Vlds[2 * 4096];
    __shared__ unsigned short Wlds[4 * 2048];   // per-wave [row 32][64] swizzled

    const int tid = threadIdx.x;
    const int lane = tid & 63, w = tid >> 6;
    const int lr = lane & 15, lg = lane >> 4;

    // XCD-cluster decode: 1536 blocks = 8 xcd x 12 groups x 16 qt (bijective)
    const int lin = blockIdx.x;
    const int xcd = lin & 7, rem = lin >> 3;        // rem 0..191
    const int gid = xcd * 12 + (rem >> 4);          // 0..95
    const int qt = rem & 15;
    const int half = gid >> 5, bh = gid & 31;       // half 0..2, bh 0..31
    const int q0 = qt * 128 + w * 32;
    const int kbeg = half * 11;
    const int kend = (half == 2) ? 32 : (kbeg + 11);

    unsigned short* wl = &Wlds[w * 2048];
    unsigned short* __restrict__ Op = (half == 0) ? Op0 : ((half == 1) ? Op1 : Op2);
    float* __restrict__ Sw = (half == 0) ? Sw0 : ((half == 1) ? Sw1 : Sw2);

    // ---- staging addressing (each wave stages 16 rows of each 64x64 tile)
    const int srow = w * 16 + (lane >> 2);     // tile row 0..63
    const int sc = (lane & 3) * 2;             // 16B-chunk pair {sc, sc+1} of 8
    const unsigned short* Kg = Kb + (bh * 2048 + srow) * 64 + sc * 8;  // + kt*4096
    const unsigned short* Vg = Vt + (bh * 64 + srow) * 2048 + sc * 8;  // + kt*64
    const int swz0 = srow * 64 + ((sc ^ (srow & 7)) * 8);
    const int swz1 = srow * 64 + (((sc + 1) ^ (srow & 7)) * 8);

    // ---- Q fragments (B-operand): Q[q0+g*16+lr][lg*8+e (+32)]
    bf16x8 qf[2][2];
    #pragma unroll
    for (int g = 0; g < 2; ++g) {
        const unsigned short* qp = Qb + (bh * 2048 + q0 + g * 16 + lr) * 64 + lg * 8;
        qf[g][0] = *(const bf16x8*)qp;
        qf[g][1] = *(const bf16x8*)(qp + 32);
    }
    float q2v[2];
    q2v[0] = q2s[bh * 2048 + q0 + lr];
    q2v[1] = q2s[bh * 2048 + q0 + 16 + lr];

    f32x4 oacc[2][4] = {};
    float sumw[2] = {0.f, 0.f};

    // ---- prologue: stage kbeg into buf 0
    uint4 ks0, ks1, vs0, vs1;
    {
        const unsigned short* kp = Kg + kbeg * 4096;
        ks0 = *(const uint4*)kp; ks1 = *(const uint4*)(kp + 8);
        const unsigned short* vp = Vg + kbeg * 64;
        vs0 = *(const uint4*)vp; vs1 = *(const uint4*)(vp + 8);
    }
    *(uint4*)&Klds[swz0] = ks0; *(uint4*)&Klds[swz1] = ks1;
    *(uint4*)&Vlds[swz0] = vs0; *(uint4*)&Vlds[swz1] = vs1;
    __syncthreads();

    int buf = 0;
    for (int kt = kbeg; kt < kend; ++kt) {
        const int k0 = kt * 64;
        const bool more = (kt + 1 < kend);

        // issue next-tile stage loads early (hide HBM/L2 latency under compute)
        if (more) {
            const unsigned short* kp = Kg + (kt + 1) * 4096;
            ks0 = *(const uint4*)kp; ks1 = *(const uint4*)(kp + 8);
            const unsigned short* vp = Vg + (kt + 1) * 64;
            vs0 = *(const uint4*)vp; vs1 = *(const uint4*)(vp + 8);
        }

        f32x4 k2v[4];
        #pragma unroll
        for (int nf = 0; nf < 4; ++nf)
            k2v[nf] = *(const f32x4*)&k2s[bh * 2048 + k0 + nf * 16 + lg * 4];

        // ---- QK^T swapped, K frags from swizzled LDS
        f32x4 sa[2][4] = {};
        const unsigned short* kb = &Klds[buf * 4096];
        __builtin_amdgcn_s_setprio(1);
        #pragma unroll
        for (int nf = 0; nf < 4; ++nf) {
            const int row = nf * 16 + lr;
            bf16x8 kf0 = *(const bf16x8*)&kb[row * 64 + ((lg ^ (row & 7)) * 8)];
            bf16x8 kf1 = *(const bf16x8*)&kb[row * 64 + (((4 + lg) ^ (row & 7)) * 8)];
            #pragma unroll
            for (int g = 0; g < 2; ++g) {
                sa[g][nf] = MFMA(kf0, qf[g][0], sa[g][nf]);
                sa[g][nf] = MFMA(kf1, qf[g][1], sa[g][nf]);
            }
        }
        __builtin_amdgcn_s_setprio(0);

        // ---- Shepard weights (sqrt-free), pack bf16, stash W[q][k] in slab
        #pragma unroll
        for (int g = 0; g < 2; ++g) {
            const int row = g * 16 + lr;
            #pragma unroll
            for (int nf = 0; nf < 4; ++nf) {
                float wv[4];
                #pragma unroll
                for (int r = 0; r < 4; ++r) {
                    float d2 = fmaf(-2.0f, sa[g][nf][r], q2v[g] + k2v[nf][r]);
                    d2 = fmaxf(d2, 1e-8f);
                    wv[r] = __builtin_amdgcn_rcpf(d2);
                    sumw[g] += wv[r];
                }
                uint2 pk;
                pk.x = cvtpk(wv[0], wv[1]);
                pk.y = cvtpk(wv[2], wv[3]);
                const int c = 2 * nf + (lg >> 1);
                *(uint2*)&wl[row * 64 + ((c ^ (row & 7)) * 8) + (lg & 1) * 4] = pk;
            }
        }

        // ---- PV: A = W frags from slab, B = V frags from swizzled LDS
        bf16x8 pa[2][2];
        #pragma unroll
        for (int g = 0; g < 2; ++g) {
            const int row = g * 16 + lr;
            pa[g][0] = *(const bf16x8*)&wl[row * 64 + ((lg ^ (row & 7)) * 8)];
            pa[g][1] = *(const bf16x8*)&wl[row * 64 + (((4 + lg) ^ (row & 7)) * 8)];
        }
        const unsigned short* vb = &Vlds[buf * 4096];
        __builtin_amdgcn_s_setprio(1);
        #pragma unroll
        for (int vf = 0; vf < 4; ++vf) {
            const int row = vf * 16 + lr;
            bf16x8 v0 = *(const bf16x8*)&vb[row * 64 + ((lg ^ (row & 7)) * 8)];
            bf16x8 v1 = *(const bf16x8*)&vb[row * 64 + (((4 + lg) ^ (row & 7)) * 8)];
            #pragma unroll
            for (int g = 0; g < 2; ++g) {
                oacc[g][vf] = MFMA(pa[g][0], v0, oacc[g][vf]);
                oacc[g][vf] = MFMA(pa[g][1], v1, oacc[g][vf]);
            }
        }
        __builtin_amdgcn_s_setprio(0);

        // ---- write staged regs into the other buffer, sync, swap
        if (more) {
            const int bo = (buf ^ 1) * 4096;
            *(uint4*)&Klds[bo + swz0] = ks0; *(uint4*)&Klds[bo + swz1] = ks1;
            *(uint4*)&Vlds[bo + swz0] = vs0; *(uint4*)&Vlds[bo + swz1] = vs1;
            __syncthreads();
            buf ^= 1;
        }
    }

    // wave-reduce sum-of-weights (lanes with same lr cover disjoint k)
    #pragma unroll
    for (int g = 0; g < 2; ++g) {
        sumw[g] += __shfl_xor(sumw[g], 16, 64);
        sumw[g] += __shfl_xor(sumw[g], 32, 64);
    }

    // epilogue: store unnormalized partial O (bf16) + partial sums
    #pragma unroll
    for (int g = 0; g < 2; ++g) {
        #pragma unroll
        for (int vf = 0; vf < 4; ++vf) {
            #pragma unroll
            for (int r = 0; r < 4; ++r) {
                const int t = q0 + g * 16 + lg * 4 + r;
                const int dh = vf * 16 + lr;
                Op[(bh * 2048 + t) * 64 + dh] = f2b(oacc[g][vf][r]);
            }
        }
    }
    if (lg == 0) {
        Sw[bh * 2048 + q0 + lr]      = sumw[0];
        Sw[bh * 2048 + q0 + 16 + lr] = sumw[1];
    }
}

// ---------------------------------------------------------------------------
// Combine: H[tok][h*64+dh] = (o0+o1+o2)/(EPS+s0+s1+s2) * G, bf16. 8 elem/thr.
// ---------------------------------------------------------------------------
__global__ __launch_bounds__(256)
void sga_combine(const unsigned short* __restrict__ Op0, const unsigned short* __restrict__ Op1,
                 const unsigned short* __restrict__ Op2,
                 const float* __restrict__ Sw0, const float* __restrict__ Sw1,
                 const float* __restrict__ Sw2,
                 const unsigned short* __restrict__ Gb, unsigned short* __restrict__ Hb)
{
    const int idx = blockIdx.x * 256 + threadIdx.x;   // one per 8 dh
    const int t16 = idx >> 3;                          // bh*2048 + t
    const int dq = (idx & 7) << 3;
    u16x8 a = *(const u16x8*)&Op0[t16 * 64 + dq];
    u16x8 b = *(const u16x8*)&Op1[t16 * 64 + dq];
    u16x8 c = *(const u16x8*)&Op2[t16 * 64 + dq];
    u16x8 g = *(const u16x8*)&Gb[t16 * 64 + dq];
    const float s = Sw0[t16] + Sw1[t16] + Sw2[t16];
    const float inv = __builtin_amdgcn_rcpf(EPS + s);
    const int bh = t16 >> 11, tloc = t16 & 2047;
    const int bb = bh >> 4, h = bh & 15;
    u16x8 o;
    #pragma unroll
    for (int j = 0; j < 8; ++j)
        o[j] = f2b((b2f(a[j]) + b2f(b[j]) + b2f(c[j])) * inv * b2f(g[j]));
    *(u16x8*)&Hb[(bb * 2048 + tloc) * 1024 + h * 64 + dq] = o;
}

// ---------------------------------------------------------------------------
// GEMM2, m97 structure, BM=64 x BN=128 (512 blocks -> 2 blocks/CU):
// Y = Hb*Woutb^T + bout
// ---------------------------------------------------------------------------
__global__ __launch_bounds__(256)
void sga_gemm2(const unsigned short* __restrict__ Hb, const unsigned short* __restrict__ Wb,
               const float* __restrict__ bout, float* __restrict__ Y)
{
    __shared__ unsigned short As[64 * 64];
    __shared__ unsigned short Bs[128 * 64];
    const int tid = threadIdx.x;
    const int lane = tid & 63, w = tid >> 6;
    const int lr = lane & 15, lg = lane >> 4;
    const int wm = w & 1, wn = w >> 1;
    const int m0 = blockIdx.y * 64, n0 = blockIdx.x * 128;

    const int sr = tid >> 3, sc8 = tid & 7;
    const int gch = sc8 ^ (sr & 7);
    const unsigned short* aBase = Hb + (m0 + sr) * 1024 + gch * 8;
    const unsigned short* bBase = Wb + (n0 + sr) * 1024 + gch * 8;
    unsigned short* aDst = &As[w * 512];
    unsigned short* bDst = &Bs[w * 512];

    f32x4 acc[2][4] = {};

    for (int kt = 0; kt < 16; ++kt) {
        __syncthreads();
        #pragma unroll
        for (int c = 0; c < 2; ++c)
            gl_lds16(aBase + c * 32768 + kt * 64, aDst + c * 2048);
        #pragma unroll
        for (int c = 0; c < 4; ++c)
            gl_lds16(bBase + c * 32768 + kt * 64, bDst + c * 2048);
        __syncthreads();

        #pragma unroll
        for (int ks = 0; ks < 2; ++ks) {
            bf16x8 af[2], bfr[4];
            #pragma unroll
            for (int i = 0; i < 2; ++i) {
                const int row = wm * 32 + i * 16 + lr;
                af[i] = *(const bf16x8*)&As[row * 64 + (((ks * 4 + lg) ^ (row & 7)) * 8)];
            }
            #pragma unroll
            for (int i = 0; i < 4; ++i) {
                const int row = wn * 64 + i * 16 + lr;
                bfr[i] = *(const bf16x8*)&Bs[row * 64 + (((ks * 4 + lg) ^ (row & 7)) * 8)];
            }
            #pragma unroll
            for (int mi = 0; mi < 2; ++mi)
                #pragma unroll
                for (int ni = 0; ni < 4; ++ni)
                    acc[mi][ni] = MFMA(af[mi], bfr[ni], acc[mi][ni]);
        }
    }

    #pragma unroll
    for (int mf = 0; mf < 2; ++mf) {
        const int m = m0 + wm * 32 + mf * 16 + lg * 4;
        #pragma unroll
        for (int nf = 0; nf < 4; ++nf) {
            const int n = n0 + wn * 64 + nf * 16 + lr;
            const float bz = bout[n];
            f32x4 v = acc[mf][nf];
            #pragma unroll
            for (int r = 0; r < 4; ++r)
                Y[(m + r) * 1024 + n] = v[r] + bz;
        }
    }
}

extern "C" void kernel_launch(void* const* d_in, const int* in_sizes, int n_in,
                              void* d_out, int out_size, void* d_ws, size_t ws_size,
                              hipStream_t stream) {
    const float* X    = (const float*)d_in[0];
    const float* Win  = (const float*)d_in[1];
    const float* bin  = (const float*)d_in[2];
    const float* Wout = (const float*)d_in[3];
    const float* bout = (const float*)d_in[4];
    float* Y = (float*)d_out;

    const int PER = 32 * 2048 * 64;        // 4,194,304 elems per Q/K/V/G tensor
    unsigned short* Qb   = (unsigned short*)d_ws;
    unsigned short* Kb   = Qb + PER;
    unsigned short* Vt   = Kb + PER;
    unsigned short* Gb   = Vt + PER;
    unsigned short* Hb   = Gb + PER;       // 4096*1024
    unsigned short* Xb   = Hb + PER;
    unsigned short* Winb = Xb + PER;
    unsigned short* Woutb= Winb + PER;
    float* q2s = (float*)(Woutb + 1024 * 1024);
    float* k2s = q2s + 32 * 2048;
    float* Sw0 = k2s + 32 * 2048;
    float* Sw1 = Sw0 + 32 * 2048;
    float* Sw2 = Sw1 + 32 * 2048;
    unsigned short* Op2 = (unsigned short*)(Sw2 + 32 * 2048);
    // partial-O buffers 0/1 alias Xb/Winb (dead after gemm1; stream is serial)
    unsigned short* Op0 = Xb;
    unsigned short* Op1 = Winb;

    sga_f2b_all<<<4608, 256, 0, stream>>>(X, Win, Wout, Xb, Winb, Woutb);
    sga_gemm1<<<dim3(32, 32), 256, 0, stream>>>(Xb, Winb, bin, Qb, Kb, Vt, Gb, q2s, k2s);
    sga_attn <<<1536, 256, 0, stream>>>(Qb, Kb, Vt, q2s, k2s, Op0, Op1, Op2, Sw0, Sw1, Sw2);
    sga_combine<<<2048, 256, 0, stream>>>(Op0, Op1, Op2, Sw0, Sw1, Sw2, Gb, Hb);
    sga_gemm2<<<dim3(8, 64), 256, 0, stream>>>(Hb, Woutb, bout, Y);
}